// Round 2
// baseline (455.136 us; speedup 1.0000x reference)
//
#include <hip/hip_runtime.h>
#include <math.h>

// MoE gate: logits = x[16384,2048] @ W^T[2048,64]; top-8; softmax over top-8.
//
// Round-4 structure. Round-3 failed three ways: (a) register prefetch spilled
// (WRITE_SIZE 1MB->133MB) under the 128-VGPR cap of 1024-thr blocks, (b) 16-wave
// barrier lockstep at 1 block/CU (VALUBusy 24%), (c) swizzle only spread 8 slots.
// Fixes:
//   grid = 256 blocks (64 tokens), block = 512 thr = 8 waves, NO barriers in
//   the main loop. Wave w owns k-slice [w*256, w*256+256) for all 64 tokens x
//   all 64 experts (acc[64]; 512-thr block + launch_bounds(512,2) -> 256-VGPR
//   cap, so acc[64] fits without spill).
//   x staged per-wave via async global_load_lds (no registers -> nothing to
//   spill), double-buffered 4KB chunks (16 k-floats x 64 tokens), counted
//   s_waitcnt vmcnt(4) so next chunk's loads fly under the 1024-FMA phase.
//   LDS dest linear (global_load_lds requirement); swizzle done by
//   pre-swizzling the GLOBAL source granule (both-sides involution):
//     write: LDS(row r, col c) <- global granule c ^ (r&3)
//     read:  global granule g at LDS col g ^ (r&3)
//   W read via wave-uniform scalar loads (e, k wave-invariant) -> s_load, zero
//   vector-memory cost.
//   Epilogue (proven in round-2): atomicAdd partials into logits[64][64] in
//   LDS (region reuse after compute), wave 0 does per-lane top-8 + softmax.

#define H_DIM 2048
#define N_EXP 64
#define TOPK 8
#define TOK 64
#define NW 8                   // waves per block
#define KSL (H_DIM / NW)       // 256 k per wave slice
#define CH 16                  // k-floats per staged chunk
#define NIT (KSL / CH)         // 16
#define BUFB (TOK * CH * 4)    // 4096 B per buffer
#define WREG (2 * BUFB)        // 8 KB per-wave LDS region (double-buffered)

__global__ __launch_bounds__(512, 2) void moe_gate_kernel(
    const float* __restrict__ x, const float* __restrict__ w,
    float* __restrict__ out, int n_tokens) {
  __shared__ float xs[NW * WREG / 4];  // 16384 floats = 64 KB

  const int tid = threadIdx.x;
  const int l = tid & 63;
  const int wave = tid >> 6;
  const int kh = __builtin_amdgcn_readfirstlane(wave);
  const int t0 = blockIdx.x * TOK;

  // staging source: load j covers token rows j*16 + (l>>2), granule (16B) lc
  // pre-swizzled so the linear LDS write lands in swizzled layout
  const int lr = l >> 2;              // row within a 16-row group
  const int lc = (l & 3) ^ (lr & 3);  // swizzled source granule (involution)
  const char* gl =
      (const char*)(x + (size_t)(t0 + lr) * H_DIM + kh * KSL) + lc * 16;
  char* const lwf = (char*)xs + wave * WREG;  // wave-private, wave-uniform

  float acc[N_EXP];
#pragma unroll
  for (int e = 0; e < N_EXP; ++e) acc[e] = 0.f;

  // async-stage chunk ii into buffer (ii&1): 4 x 1KB direct-to-LDS
  auto stage = [&](int ii) {
    const char* g = gl + ii * (CH * 4);
    char* lb = lwf + (ii & 1) * BUFB;
#pragma unroll
    for (int j = 0; j < 4; ++j)
      __builtin_amdgcn_global_load_lds(
          (const __attribute__((address_space(1))) void*)(g +
              (size_t)j * (16 * H_DIM * 4)),
          (__attribute__((address_space(3))) void*)(lb + j * 1024), 16, 0, 0);
  };

  stage(0);

#pragma unroll 1
  for (int i = 0; i < NIT; ++i) {
    if (i + 1 < NIT) {
      stage(i + 1);  // issue next chunk first; it stays in flight (counted wait)
      asm volatile("s_waitcnt vmcnt(4)" ::: "memory");
    } else {
      asm volatile("s_waitcnt vmcnt(0)" ::: "memory");
    }
    __builtin_amdgcn_sched_barrier(0);

    // lane = token: read this lane's 16 k-floats (swizzled cols)
    const char* rb = lwf + (i & 1) * BUFB + l * (CH * 4);
    float xv[CH];
#pragma unroll
    for (int g4 = 0; g4 < 4; ++g4) {
      float4 v = *reinterpret_cast<const float4*>(rb + ((g4 ^ (l & 3)) << 4));
      xv[g4 * 4 + 0] = v.x;
      xv[g4 * 4 + 1] = v.y;
      xv[g4 * 4 + 2] = v.z;
      xv[g4 * 4 + 3] = v.w;
    }

    const float* wrb = w + kh * KSL + i * CH;  // wave-uniform -> s_load
#pragma unroll
    for (int e = 0; e < N_EXP; ++e) {
      const float* wr = wrb + (size_t)e * H_DIM;
#pragma unroll
      for (int k = 0; k < CH; ++k) acc[e] = fmaf(xv[k], wr[k], acc[e]);
    }
  }

  // ---- reduce 8 k-slice partials into logits[e][t] (first 16KB, reused) ----
  __syncthreads();  // all waves done with their staging regions
  for (int z = tid; z < N_EXP * TOK; z += 512) xs[z] = 0.f;
  __syncthreads();
#pragma unroll
  for (int e = 0; e < N_EXP; ++e) atomicAdd(&xs[e * TOK + l], acc[e]);
  __syncthreads();

  if (wave != 0) return;

  // ---- wave 0: per-lane top-8 over 64 logits (lane = token) ----
  float lg[N_EXP];
#pragma unroll
  for (int e = 0; e < N_EXP; ++e) lg[e] = xs[e * TOK + l];

  float bw[TOPK];
  int bi[TOPK];
#pragma unroll
  for (int k = 0; k < TOPK; ++k) {
    float m = lg[0];
    int mi = 0;
#pragma unroll
    for (int e = 1; e < N_EXP; ++e) {
      if (lg[e] > m) {  // strict > keeps lowest index on tie (lax.top_k)
        m = lg[e];
        mi = e;
      }
    }
    bw[k] = m;
    bi[k] = mi;
#pragma unroll
    for (int e = 0; e < N_EXP; ++e)
      if (e == mi) lg[e] = -INFINITY;
  }

  // softmax over top-8 == full softmax renormalized to top-8 (exact)
  const float mx = bw[0];
  float ew[TOPK];
  float s = 0.f;
#pragma unroll
  for (int k = 0; k < TOPK; ++k) {
    ew[k] = expf(bw[k] - mx);
    s += ew[k];
  }
  const float inv = 1.f / s;

  float4 w0, w1, i0, i1;
  w0.x = ew[0] * inv; w0.y = ew[1] * inv; w0.z = ew[2] * inv; w0.w = ew[3] * inv;
  w1.x = ew[4] * inv; w1.y = ew[5] * inv; w1.z = ew[6] * inv; w1.w = ew[7] * inv;
  i0.x = (float)bi[0]; i0.y = (float)bi[1]; i0.z = (float)bi[2]; i0.w = (float)bi[3];
  i1.x = (float)bi[4]; i1.y = (float)bi[5]; i1.z = (float)bi[6]; i1.w = (float)bi[7];

  const int t = t0 + l;
  float4* ow = reinterpret_cast<float4*>(out + (size_t)t * TOPK);
  ow[0] = w0;
  ow[1] = w1;
  float4* oi =
      reinterpret_cast<float4*>(out + (size_t)n_tokens * TOPK + (size_t)t * TOPK);
  oi[0] = i0;
  oi[1] = i1;
}

extern "C" void kernel_launch(void* const* d_in, const int* in_sizes, int n_in,
                              void* d_out, int out_size, void* d_ws,
                              size_t ws_size, hipStream_t stream) {
  const float* x = (const float*)d_in[0];
  const float* w = (const float*)d_in[1];
  float* out = (float*)d_out;
  const int n_tokens = in_sizes[0] / H_DIM;  // 16384
  const int n_blocks = n_tokens / TOK;       // 256
  moe_gate_kernel<<<n_blocks, 512, 0, stream>>>(x, w, out, n_tokens);
}

// Round 3
// 330.892 us; speedup vs baseline: 1.3755x; 1.3755x over previous
//
#include <hip/hip_runtime.h>
#include <math.h>

// MoE gate: logits = x[16384,2048] @ W^T[2048,64]; top-8; softmax over top-8.
//
// Round-5. Round-4 diagnosis: VALUBusy 11.7% == essential-FMA only; waves
// stalled on the scalar W stream (64 s_load_dwordx16/iter, K$-miss ~250cyc,
// ~3 in flight under the 112-SGPR budget). Fix: W is wave-uniform (lane ==
// token), so feed it via LDS BROADCAST (uniform ds_read_b128, conflict-free)
// staged with the same async global_load_lds double-buffer as x. Scalar pipe
// leaves the critical path; ds latency hidden by the unrolled 64-expert body.
//
//   grid = 256 blocks (64 tokens), block = 512 thr = 8 waves, no main-loop
//   barriers. Wave w owns k-slice [w*256, w*256+256) for all 64 experts
//   (acc[64]; 512-thr + launch_bounds(512,2) -> 256-VGPR cap, no spill).
//   Per chunk (16 k): stage x[64 tok][16k] (4 KB) + W[64 exp][16k] (4 KB),
//   8 global_load_lds each 1 KB, double-buffered, counted s_waitcnt vmcnt(8).
//   x swizzle (both-sides involution, 8-slot-even => 8-cyc b128 floor):
//     write: source granule (l&3) ^ ((l>>3)&3), linear LDS dest
//     read:  slot g ^ ((token>>1)&3)
//   W unswizzled: uniform-address reads broadcast, never conflict.
//   Epilogue: atomicAdd partials into logits[64][64] overlaid on x region,
//   wave 0 per-lane top-8 (strict >, lax.top_k ties) + softmax over top-8.

#define H_DIM 2048
#define N_EXP 64
#define TOPK 8
#define TOK 64
#define NW 8
#define KSL (H_DIM / NW)   // 256 k per wave
#define CH 16              // k per chunk
#define NIT (KSL / CH)     // 16
#define XBUF 4096          // 64 tok * 16 k * 4 B
#define WBUF 4096          // 64 exp * 16 k * 4 B

__global__ __launch_bounds__(512, 2) void moe_gate_kernel(
    const float* __restrict__ x, const float* __restrict__ w,
    float* __restrict__ out, int n_tokens) {
  // 128 KB: [0,64K) x double-buffers (8 KB/wave), [64K,128K) W double-buffers.
  __shared__ float lds[32768];
  char* const ldsb = (char*)lds;

  const int tid = threadIdx.x;
  const int l = tid & 63;
  const int wave = tid >> 6;
  const int kh = __builtin_amdgcn_readfirstlane(wave);  // k-slice id, SGPR
  const int t0 = blockIdx.x * TOK;

  char* const xbase = ldsb + kh * (2 * XBUF);
  char* const wbase = ldsb + 65536 + kh * (2 * WBUF);

  // staging: load j covers rows/experts j*16 + (l>>2), 4 lanes x 16 B per row
  const int lr = l >> 2;
  const int lcx = (l & 3) ^ ((l >> 3) & 3);  // pre-swizzled x source granule
  const char* gx =
      (const char*)(x + (size_t)(t0 + lr) * H_DIM + kh * KSL) + lcx * 16;
  const char* gw =
      (const char*)(w + (size_t)lr * H_DIM + kh * KSL) + (l & 3) * 16;

  float acc[N_EXP];
#pragma unroll
  for (int e = 0; e < N_EXP; ++e) acc[e] = 0.f;

  auto stage = [&](int ii) {
    const char* gxc = gx + ii * (CH * 4);
    const char* gwc = gw + ii * (CH * 4);
    char* xb = xbase + (ii & 1) * XBUF;
    char* wb = wbase + (ii & 1) * WBUF;
#pragma unroll
    for (int j = 0; j < 4; ++j) {
      __builtin_amdgcn_global_load_lds(
          (const __attribute__((address_space(1))) void*)(gxc +
              (size_t)j * (16 * H_DIM * 4)),
          (__attribute__((address_space(3))) void*)(xb + j * 1024), 16, 0, 0);
      __builtin_amdgcn_global_load_lds(
          (const __attribute__((address_space(1))) void*)(gwc +
              (size_t)j * (16 * H_DIM * 4)),
          (__attribute__((address_space(3))) void*)(wb + j * 1024), 16, 0, 0);
    }
  };

  stage(0);

#pragma unroll 1
  for (int i = 0; i < NIT; ++i) {
    if (i + 1 < NIT) {
      stage(i + 1);  // 8 more in flight; counted wait keeps them flying
      asm volatile("s_waitcnt vmcnt(8)" ::: "memory");
    } else {
      asm volatile("s_waitcnt vmcnt(0)" ::: "memory");
    }
    __builtin_amdgcn_sched_barrier(0);

    // lane = token: this lane's 16 k-floats (swizzled slots, 8-cyc floor)
    const char* xr = xbase + (i & 1) * XBUF + l * 64;
    const int xs_ = (l >> 1) & 3;
    float xv[CH];
#pragma unroll
    for (int g = 0; g < 4; ++g) {
      float4 v = *reinterpret_cast<const float4*>(xr + ((g ^ xs_) << 4));
      xv[g * 4 + 0] = v.x;
      xv[g * 4 + 1] = v.y;
      xv[g * 4 + 2] = v.z;
      xv[g * 4 + 3] = v.w;
    }

    const char* wr0 = wbase + (i & 1) * WBUF;
#pragma unroll
    for (int e = 0; e < N_EXP; ++e) {
      // uniform address -> ds_read_b128 broadcast (conflict-free)
      const float4* wp = reinterpret_cast<const float4*>(wr0 + e * 64);
      float4 w0 = wp[0], w1 = wp[1], w2 = wp[2], w3 = wp[3];
      acc[e] = fmaf(xv[0], w0.x, acc[e]);
      acc[e] = fmaf(xv[1], w0.y, acc[e]);
      acc[e] = fmaf(xv[2], w0.z, acc[e]);
      acc[e] = fmaf(xv[3], w0.w, acc[e]);
      acc[e] = fmaf(xv[4], w1.x, acc[e]);
      acc[e] = fmaf(xv[5], w1.y, acc[e]);
      acc[e] = fmaf(xv[6], w1.z, acc[e]);
      acc[e] = fmaf(xv[7], w1.w, acc[e]);
      acc[e] = fmaf(xv[8], w2.x, acc[e]);
      acc[e] = fmaf(xv[9], w2.y, acc[e]);
      acc[e] = fmaf(xv[10], w2.z, acc[e]);
      acc[e] = fmaf(xv[11], w2.w, acc[e]);
      acc[e] = fmaf(xv[12], w3.x, acc[e]);
      acc[e] = fmaf(xv[13], w3.y, acc[e]);
      acc[e] = fmaf(xv[14], w3.z, acc[e]);
      acc[e] = fmaf(xv[15], w3.w, acc[e]);
    }
  }

  // ---- reduce 8 k-slice partials into logits[e][t] (x region, reused) ----
  __syncthreads();  // all waves done with their staging regions
  for (int z = tid; z < N_EXP * TOK; z += 512) lds[z] = 0.f;
  __syncthreads();
#pragma unroll
  for (int e = 0; e < N_EXP; ++e) atomicAdd(&lds[e * TOK + l], acc[e]);
  __syncthreads();

  if (wave != 0) return;

  // ---- wave 0: per-lane top-8 over 64 logits (lane = token) ----
  float lg[N_EXP];
#pragma unroll
  for (int e = 0; e < N_EXP; ++e) lg[e] = lds[e * TOK + l];

  float bw[TOPK];
  int bi[TOPK];
#pragma unroll
  for (int k = 0; k < TOPK; ++k) {
    float m = lg[0];
    int mi = 0;
#pragma unroll
    for (int e = 1; e < N_EXP; ++e) {
      if (lg[e] > m) {  // strict > keeps lowest index on tie (lax.top_k)
        m = lg[e];
        mi = e;
      }
    }
    bw[k] = m;
    bi[k] = mi;
#pragma unroll
    for (int e = 0; e < N_EXP; ++e)
      if (e == mi) lg[e] = -INFINITY;
  }

  // softmax over top-8 == full softmax renormalized to top-8 (exact)
  const float mx = bw[0];
  float ew[TOPK];
  float s = 0.f;
#pragma unroll
  for (int k = 0; k < TOPK; ++k) {
    ew[k] = expf(bw[k] - mx);
    s += ew[k];
  }
  const float inv = 1.f / s;

  float4 w0, w1, i0, i1;
  w0.x = ew[0] * inv; w0.y = ew[1] * inv; w0.z = ew[2] * inv; w0.w = ew[3] * inv;
  w1.x = ew[4] * inv; w1.y = ew[5] * inv; w1.z = ew[6] * inv; w1.w = ew[7] * inv;
  i0.x = (float)bi[0]; i0.y = (float)bi[1]; i0.z = (float)bi[2]; i0.w = (float)bi[3];
  i1.x = (float)bi[4]; i1.y = (float)bi[5]; i1.z = (float)bi[6]; i1.w = (float)bi[7];

  const int t = t0 + l;
  float4* ow = reinterpret_cast<float4*>(out + (size_t)t * TOPK);
  ow[0] = w0;
  ow[1] = w1;
  float4* oi =
      reinterpret_cast<float4*>(out + (size_t)n_tokens * TOPK + (size_t)t * TOPK);
  oi[0] = i0;
  oi[1] = i1;
}

extern "C" void kernel_launch(void* const* d_in, const int* in_sizes, int n_in,
                              void* d_out, int out_size, void* d_ws,
                              size_t ws_size, hipStream_t stream) {
  const float* x = (const float*)d_in[0];
  const float* w = (const float*)d_in[1];
  float* out = (float*)d_out;
  const int n_tokens = in_sizes[0] / H_DIM;  // 16384
  const int n_blocks = n_tokens / TOK;       // 256
  moe_gate_kernel<<<n_blocks, 512, 0, stream>>>(x, w, out, n_tokens);
}

// Round 4
// 264.049 us; speedup vs baseline: 1.7237x; 1.2531x over previous
//
#include <hip/hip_runtime.h>
#include <math.h>

// MoE gate: logits = x[16384,2048] @ W^T[2048,64]; top-8; softmax over top-8.
//
// Round-6. Round-5 (209us, VALUBusy 40%) was LDS-instruction-bound: 256
// W-broadcast ds_read_b128 per 1024 FMAs per iter (1:4) co-saturated the
// per-CU LDS pipe with the VALU. Fix: register-block BOTH operands.
//   lane = (tr, er) = (l>>3, l&7): 8-token x 8-expert tile per lane,
//   acc[8][8]=64 VGPR. Per 4-k sub-chunk: 8 x-reads + 8 W-reads (b128)
//   feed 256 FMAs -> 16 FMA per LDS instr (4x fewer LDS ops than round-5).
//   Per instruction: 8 distinct addresses (er-lanes multicast same addr,
//   free), slot swizzle c^(tr&3) / c^(er&3) lands them 2-per-bank (free).
//   Staging pre-swizzles the GLOBAL source granule (both-sides involution):
//   granule g at slot p=g^((row>>3)&3), row = j*16 + (l>>2).
// Carried from round-5 (proven): grid 256 x 512 thr = 8 waves, wave kh owns
//   k-slice [kh*256,+256); async global_load_lds double-buffer, counted
//   s_waitcnt vmcnt(8), no main-loop barriers; atomicAdd partial reduce into
//   logits[e][t] + wave-0 per-lane top-8 (strict >) + softmax over top-8.

#define H_DIM 2048
#define N_EXP 64
#define TOPK 8
#define TOK 64
#define NW 8
#define KSL (H_DIM / NW)   // 256 k per wave
#define CH 16              // k per chunk
#define NIT (KSL / CH)     // 16
#define XBUF 4096          // 64 tok * 16 k * 4 B
#define WBUF 4096          // 64 exp * 16 k * 4 B

__global__ __launch_bounds__(512, 2) void moe_gate_kernel(
    const float* __restrict__ x, const float* __restrict__ w,
    float* __restrict__ out, int n_tokens) {
  // 128 KB: [0,64K) x double-buffers (8 KB/wave), [64K,128K) W double-buffers.
  __shared__ float lds[32768];
  char* const ldsb = (char*)lds;

  const int tid = threadIdx.x;
  const int l = tid & 63;
  const int wave = tid >> 6;
  const int kh = __builtin_amdgcn_readfirstlane(wave);  // k-slice id, SGPR
  const int t0 = blockIdx.x * TOK;

  char* const xbase = ldsb + kh * (2 * XBUF);
  char* const wbase = ldsb + 65536 + kh * (2 * WBUF);

  const int tr = l >> 3;  // token-row group (8 tokens: tr*8..tr*8+7)
  const int er = l & 7;   // expert group   (8 experts: er*8..er*8+7)
  const int xsw = tr & 3; // x read-slot swizzle
  const int wsw = er & 3; // W read-slot swizzle

  // staging: load j covers rows j*16 + (l>>2); source granule pre-swizzled so
  // the linear LDS write (lane*16) lands row-major with slot = g ^ ((row>>3)&3)
  const int lr4 = l >> 2;
  const char* gxp[4];
  const char* gwp[4];
#pragma unroll
  for (int j = 0; j < 4; ++j) {
    const int row = j * 16 + lr4;
    const int g = (l & 3) ^ ((2 * j + (l >> 5)) & 3);
    gxp[j] = (const char*)(x + (size_t)(t0 + row) * H_DIM + kh * KSL) + g * 16;
    gwp[j] = (const char*)(w + (size_t)row * H_DIM + kh * KSL) + g * 16;
  }

  float acc[8][8];
#pragma unroll
  for (int a = 0; a < 8; ++a)
#pragma unroll
    for (int b = 0; b < 8; ++b) acc[a][b] = 0.f;

  auto stage = [&](int ii) {
    char* xb = xbase + (ii & 1) * XBUF;
    char* wb = wbase + (ii & 1) * WBUF;
#pragma unroll
    for (int j = 0; j < 4; ++j) {
      __builtin_amdgcn_global_load_lds(
          (const __attribute__((address_space(1))) void*)(gxp[j] +
                                                          ii * (CH * 4)),
          (__attribute__((address_space(3))) void*)(xb + j * 1024), 16, 0, 0);
      __builtin_amdgcn_global_load_lds(
          (const __attribute__((address_space(1))) void*)(gwp[j] +
                                                          ii * (CH * 4)),
          (__attribute__((address_space(3))) void*)(wb + j * 1024), 16, 0, 0);
    }
  };

  stage(0);

#pragma unroll 1
  for (int i = 0; i < NIT; ++i) {
    if (i + 1 < NIT) {
      stage(i + 1);  // 8 more in flight; counted wait keeps them flying
      asm volatile("s_waitcnt vmcnt(8)" ::: "memory");
    } else {
      asm volatile("s_waitcnt vmcnt(0)" ::: "memory");
    }
    __builtin_amdgcn_sched_barrier(0);

    const char* xr = xbase + (i & 1) * XBUF + (tr * 8) * 64;
    const char* wr = wbase + (i & 1) * WBUF + (er * 8) * 64;
#pragma unroll
    for (int c = 0; c < 4; ++c) {
      float4 xv[8], wv[8];
#pragma unroll
      for (int jt = 0; jt < 8; ++jt)
        xv[jt] =
            *reinterpret_cast<const float4*>(xr + jt * 64 + ((c ^ xsw) << 4));
#pragma unroll
      for (int je = 0; je < 8; ++je)
        wv[je] =
            *reinterpret_cast<const float4*>(wr + je * 64 + ((c ^ wsw) << 4));
#pragma unroll
      for (int jt = 0; jt < 8; ++jt)
#pragma unroll
        for (int je = 0; je < 8; ++je) {
          acc[jt][je] = fmaf(xv[jt].x, wv[je].x, acc[jt][je]);
          acc[jt][je] = fmaf(xv[jt].y, wv[je].y, acc[jt][je]);
          acc[jt][je] = fmaf(xv[jt].z, wv[je].z, acc[jt][je]);
          acc[jt][je] = fmaf(xv[jt].w, wv[je].w, acc[jt][je]);
        }
    }
  }

  // ---- reduce 8 k-slice partials into logits[e][t] (x region, reused) ----
  __syncthreads();  // all waves done reading their staging regions
  for (int z = tid; z < N_EXP * TOK; z += 512) lds[z] = 0.f;
  __syncthreads();
#pragma unroll
  for (int jt = 0; jt < 8; ++jt)
#pragma unroll
    for (int je = 0; je < 8; ++je)
      atomicAdd(&lds[(er * 8 + je) * TOK + (tr * 8 + jt)], acc[jt][je]);
  __syncthreads();

  if (wave != 0) return;

  // ---- wave 0: per-lane top-8 over 64 logits (lane = token) ----
  float lg[N_EXP];
#pragma unroll
  for (int e = 0; e < N_EXP; ++e) lg[e] = lds[e * TOK + l];

  float bw[TOPK];
  int bi[TOPK];
#pragma unroll
  for (int k = 0; k < TOPK; ++k) {
    float m = lg[0];
    int mi = 0;
#pragma unroll
    for (int e = 1; e < N_EXP; ++e) {
      if (lg[e] > m) {  // strict > keeps lowest index on tie (lax.top_k)
        m = lg[e];
        mi = e;
      }
    }
    bw[k] = m;
    bi[k] = mi;
#pragma unroll
    for (int e = 0; e < N_EXP; ++e)
      if (e == mi) lg[e] = -INFINITY;
  }

  // softmax over top-8 == full softmax renormalized to top-8 (exact)
  const float mx = bw[0];
  float ew[TOPK];
  float s = 0.f;
#pragma unroll
  for (int k = 0; k < TOPK; ++k) {
    ew[k] = expf(bw[k] - mx);
    s += ew[k];
  }
  const float inv = 1.f / s;

  float4 w0, w1, i0, i1;
  w0.x = ew[0] * inv; w0.y = ew[1] * inv; w0.z = ew[2] * inv; w0.w = ew[3] * inv;
  w1.x = ew[4] * inv; w1.y = ew[5] * inv; w1.z = ew[6] * inv; w1.w = ew[7] * inv;
  i0.x = (float)bi[0]; i0.y = (float)bi[1]; i0.z = (float)bi[2]; i0.w = (float)bi[3];
  i1.x = (float)bi[4]; i1.y = (float)bi[5]; i1.z = (float)bi[6]; i1.w = (float)bi[7];

  const int t = t0 + l;
  float4* ow = reinterpret_cast<float4*>(out + (size_t)t * TOPK);
  ow[0] = w0;
  ow[1] = w1;
  float4* oi =
      reinterpret_cast<float4*>(out + (size_t)n_tokens * TOPK + (size_t)t * TOPK);
  oi[0] = i0;
  oi[1] = i1;
}

extern "C" void kernel_launch(void* const* d_in, const int* in_sizes, int n_in,
                              void* d_out, int out_size, void* d_ws,
                              size_t ws_size, hipStream_t stream) {
  const float* x = (const float*)d_in[0];
  const float* w = (const float*)d_in[1];
  float* out = (float*)d_out;
  const int n_tokens = in_sizes[0] / H_DIM;  // 16384
  const int n_blocks = n_tokens / TOK;       // 256
  moe_gate_kernel<<<n_blocks, 512, 0, stream>>>(x, w, out, n_tokens);
}

// Round 5
// 259.713 us; speedup vs baseline: 1.7525x; 1.0167x over previous
//
#include <hip/hip_runtime.h>
#include <math.h>

// MoE gate: logits = x[16384,2048] @ W^T[2048,64]; top-8; softmax over top-8.
//
// Round-7. Round-6 (169us) was latency-bound: 128KB LDS + 256-block grid ->
// 1 block/CU = 2 waves/SIMD; acc[64]+operands hit the 128-VGPR cap, compiler
// serialized ds_read->FMA, nothing hid the LDS latency (VALUBusy 26%).
// Fixes:
//   TOK=32 per block -> grid 512; LDS 72KB -> 2 blocks/CU = 4 waves/SIMD.
//   Lane tile 4 tok x 8 exp (acc 32, ~100 VGPR) -> compiler slack to pipeline.
//   Exact conflict-free swizzles (8 distinct bank-quads per ds_read_b128,
//   8-lane multicast per address is free):
//     x granule: (tok&24) | ((tok&7) ^ ((tok>>3)&3))   [self-inverse]
//     W granule: er*8 + (je ^ er)                      [self-inverse]
//   staged by pre-swizzling the GLOBAL source lane->granule mapping, LDS dest
//   linear (global_load_lds requirement).
//   Triple-buffered CH=8 chunks, 3 gload_lds/chunk, counted vmcnt(6): two
//   chunks always in flight -> ~2 iterations (>=1000 cyc) of HBM-latency lead.
// Carried: barrier-free main loop, per-wave k-slice (kh owns [kh*256,+256)),
//   async global_load_lds, wave-0 top-8 (strict >, lax.top_k ties) + softmax.
// Epilogue: atomic-free — b128 partial stores part[kh][e][t], block-wide
//   8-way reduce into logits[e][t], wave-0 per-token top-8.

#define H_DIM 2048
#define N_EXP 64
#define TOPK 8
#define TOK 32
#define NW 8
#define KSL (H_DIM / NW)  // 256 k per wave
#define CH 8              // k per chunk
#define NIT (KSL / CH)    // 32
#define XCH 1024          // TOK*CH*4 B
#define WCH 2048          // N_EXP*CH*4 B
#define WREG (3 * (XCH + WCH))  // 9216 B per wave (triple-buffered x+W)

__global__ __launch_bounds__(512, 4) void moe_gate_kernel(
    const float* __restrict__ x, const float* __restrict__ w,
    float* __restrict__ out, int n_tokens) {
  // 72 KB: main loop = 8 wave-private 9216B staging regions.
  // Epilogue overlay: part[8][64][32] f32 (64KB) + logits[64][32] (8KB).
  __shared__ float lds[18432];
  char* const ldsb = (char*)lds;

  const int tid = threadIdx.x;
  const int l = tid & 63;
  const int wave = tid >> 6;
  const int kh = __builtin_amdgcn_readfirstlane(wave);  // k-slice id (SGPR)
  const int t0 = blockIdx.x * TOK;

  char* const wreg = ldsb + kh * WREG;  // wave-uniform staging base

  // ---- staging source (pre-swizzled, both-sides involution) ----
  // x chunk = 1KB = 1 load: lane l -> granule l; c=l>>5 (k-half), r=l&31,
  // source token = (r&24) | ((r&7) ^ ((r>>3)&3)).
  const int sc = l >> 5;
  const int sr = l & 31;
  const int stok = (sr & 24) | ((sr & 7) ^ ((sr >> 3) & 3));
  const float* gx = x + (size_t)(t0 + stok) * H_DIM + kh * KSL + sc * 4;
  // W chunk = 2KB = 2 loads (load j covers k-half c=j): er=(l>>3)&7,
  // je = (l&7)^er -> expert er*8+je.
  const int serw = (l >> 3) & 7;
  const int sje = (l & 7) ^ serw;
  const float* gwr = w + (size_t)(serw * 8 + sje) * H_DIM + kh * KSL;

  // ---- compute-side LDS byte offsets (lane tile: 4 tok x 8 exp) ----
  const int tr = l >> 3;  // token group: rows tr*4..tr*4+3
  const int er = l & 7;   // expert group: er*8..er*8+7
  int xg[4], wg[8];
#pragma unroll
  for (int jt = 0; jt < 4; ++jt) {
    const int tok = tr * 4 + jt;
    xg[jt] = ((tok & 24) | ((tok & 7) ^ ((tok >> 3) & 3))) << 4;
  }
#pragma unroll
  for (int je = 0; je < 8; ++je) wg[je] = (er * 8 + (je ^ er)) << 4;

  float acc[4][8];
#pragma unroll
  for (int a = 0; a < 4; ++a)
#pragma unroll
    for (int b = 0; b < 8; ++b) acc[a][b] = 0.f;

  // buffers: x at wreg+{0,1024,2048}, W at wreg+{3072,5120,7168}
  auto stage = [&](int ii, int xo, int wo) {
    __builtin_amdgcn_global_load_lds(
        (const __attribute__((address_space(1))) void*)(gx + ii * CH),
        (__attribute__((address_space(3))) void*)(wreg + xo), 16, 0, 0);
    __builtin_amdgcn_global_load_lds(
        (const __attribute__((address_space(1))) void*)(gwr + ii * CH),
        (__attribute__((address_space(3))) void*)(wreg + wo), 16, 0, 0);
    __builtin_amdgcn_global_load_lds(
        (const __attribute__((address_space(1))) void*)(gwr + ii * CH + 4),
        (__attribute__((address_space(3))) void*)(wreg + wo + 1024), 16, 0, 0);
  };

  int xo0 = 0, xo1 = 1024, xo2 = 2048;
  int wo0 = 3072, wo1 = 5120, wo2 = 7168;

  stage(0, xo0, wo0);
  stage(1, xo1, wo1);

#pragma unroll 1
  for (int i = 0; i < NIT; ++i) {
    if (i + 2 < NIT) {
      stage(i + 2, xo2, wo2);
      asm volatile("s_waitcnt vmcnt(6)" ::: "memory");  // chunk i drained
    } else if (i + 1 < NIT) {
      asm volatile("s_waitcnt vmcnt(3)" ::: "memory");
    } else {
      asm volatile("s_waitcnt vmcnt(0)" ::: "memory");
    }
    __builtin_amdgcn_sched_barrier(0);

    const char* xb = wreg + xo0;
    const char* wb = wreg + wo0;
#pragma unroll
    for (int c = 0; c < 2; ++c) {  // two 4-k halves
      float4 xv[4], wv[8];
#pragma unroll
      for (int jt = 0; jt < 4; ++jt)
        xv[jt] = *reinterpret_cast<const float4*>(xb + c * 512 + xg[jt]);
#pragma unroll
      for (int je = 0; je < 8; ++je)
        wv[je] = *reinterpret_cast<const float4*>(wb + c * 1024 + wg[je]);
#pragma unroll
      for (int jt = 0; jt < 4; ++jt)
#pragma unroll
        for (int je = 0; je < 8; ++je) {
          acc[jt][je] = fmaf(xv[jt].x, wv[je].x, acc[jt][je]);
          acc[jt][je] = fmaf(xv[jt].y, wv[je].y, acc[jt][je]);
          acc[jt][je] = fmaf(xv[jt].z, wv[je].z, acc[jt][je]);
          acc[jt][je] = fmaf(xv[jt].w, wv[je].w, acc[jt][je]);
        }
    }
    // rotate triple buffers (plain scalar moves)
    int tx = xo0; xo0 = xo1; xo1 = xo2; xo2 = tx;
    int tw = wo0; wo0 = wo1; wo1 = wo2; wo2 = tw;
  }

  // ---- epilogue: part[kh][exp][tok] stores (b128), reduce, top-8 ----
  __syncthreads();  // all waves done with staging regions
  float* part = lds;
#pragma unroll
  for (int je = 0; je < 8; ++je) {
    float4 v;
    v.x = acc[0][je];
    v.y = acc[1][je];
    v.z = acc[2][je];
    v.w = acc[3][je];
    *reinterpret_cast<float4*>(part + kh * (N_EXP * TOK) +
                               (er * 8 + je) * TOK + tr * 4) = v;
  }
  __syncthreads();
  float* logits = lds + NW * N_EXP * TOK;  // float offset 16384, 2048 floats
  for (int z = tid; z < N_EXP * TOK; z += 512) {
    float s = ((part[z] + part[2048 + z]) + (part[4096 + z] + part[6144 + z])) +
              ((part[8192 + z] + part[10240 + z]) +
               (part[12288 + z] + part[14336 + z]));
    logits[z] = s;
  }
  __syncthreads();

  if (tid >= TOK) return;  // 32 tokens: lanes 0..31 of wave 0

  float lg[N_EXP];
#pragma unroll
  for (int e = 0; e < N_EXP; ++e) lg[e] = logits[e * TOK + tid];

  float bw[TOPK];
  int bi[TOPK];
#pragma unroll
  for (int k = 0; k < TOPK; ++k) {
    float m = lg[0];
    int mi = 0;
#pragma unroll
    for (int e = 1; e < N_EXP; ++e) {
      if (lg[e] > m) {  // strict > keeps lowest index on tie (lax.top_k)
        m = lg[e];
        mi = e;
      }
    }
    bw[k] = m;
    bi[k] = mi;
#pragma unroll
    for (int e = 0; e < N_EXP; ++e)
      if (e == mi) lg[e] = -INFINITY;
  }

  // softmax over top-8 == full softmax renormalized to top-8 (exact)
  const float mx = bw[0];
  float ew[TOPK];
  float s = 0.f;
#pragma unroll
  for (int k = 0; k < TOPK; ++k) {
    ew[k] = expf(bw[k] - mx);
    s += ew[k];
  }
  const float inv = 1.f / s;

  float4 w0, w1, i0, i1;
  w0.x = ew[0] * inv; w0.y = ew[1] * inv; w0.z = ew[2] * inv; w0.w = ew[3] * inv;
  w1.x = ew[4] * inv; w1.y = ew[5] * inv; w1.z = ew[6] * inv; w1.w = ew[7] * inv;
  i0.x = (float)bi[0]; i0.y = (float)bi[1]; i0.z = (float)bi[2]; i0.w = (float)bi[3];
  i1.x = (float)bi[4]; i1.y = (float)bi[5]; i1.z = (float)bi[6]; i1.w = (float)bi[7];

  const int t = t0 + tid;
  float4* ow = reinterpret_cast<float4*>(out + (size_t)t * TOPK);
  ow[0] = w0;
  ow[1] = w1;
  float4* oi =
      reinterpret_cast<float4*>(out + (size_t)n_tokens * TOPK + (size_t)t * TOPK);
  oi[0] = i0;
  oi[1] = i1;
}

extern "C" void kernel_launch(void* const* d_in, const int* in_sizes, int n_in,
                              void* d_out, int out_size, void* d_ws,
                              size_t ws_size, hipStream_t stream) {
  const float* x = (const float*)d_in[0];
  const float* w = (const float*)d_in[1];
  float* out = (float*)d_out;
  const int n_tokens = in_sizes[0] / H_DIM;  // 16384
  const int n_blocks = n_tokens / TOK;       // 512
  moe_gate_kernel<<<n_blocks, 512, 0, stream>>>(x, w, out, n_tokens);
}

// Round 7
// 212.590 us; speedup vs baseline: 2.1409x; 1.2217x over previous
//
#include <hip/hip_runtime.h>
#include <math.h>

// MoE gate: logits = x[16384,2048] @ W^T[2048,64]; top-8; softmax over top-8.
//
// Round-9: bf16x3 split-MFMA (round-8 + one fix: part[] stride 1024->2048).
// Round-8's failure was self-inflicted: per-wave C fragments are 2048 floats
// (acc[2][4] x f32x4 x 64 lanes) but part[] gave each wave 1024 -> waves
// clobbered each other, garbage logits, indices absmax 63. Fragment-layout
// desk-check was clean; minimal delta this round to isolate that theory.
//
// Structure (unchanged from round-8):
//   v_mfma_f32_16x16x32_bf16 with 3-way bf16 error-compensated split
//   x = xh+xm+xl (RNE residual, exact subtractions), same for W; keep 6
//   products hh, mh, hm, lh, hl, mm -> dropped terms ~2^-25 relative, below
//   the f32 reduction-order noise of previously passing kernels.
//   - prologue kernel splits W once into d_ws (768 KB), B-frag order:
//     frag (ksg, nt, sp) at 1024 B; lane l dwordx4 at +l*16; lane holds
//     n = nt*16+(l&15), k = ksg*32+(l>>4)*8+{2p+h} (pair-order == A's).
//   - main: block = 512 thr = 8 waves = (tp in [0,2)) x (kq in [0,4));
//     wave = 32 tok x 64 exp x 512 k = 16 k-steps. Per step: 12 coalesced
//     B-frag dwordx4 (L2-resident ws), 4 x-dwordx4 global->reg (full-line
//     use, depth-2 prefetch), in-reg split -> 3 A-frags, 48 MFMAs.
//   - epilogue: part[8][2048] (64 KB) + logits[64][64] (16 KB) = 80 KB LDS;
//     k-quarter reduce, wave-0 per-lane top-8 (strict >) + softmax.
// C/D layout (m89-verified): col(=expert)=lane&15, row(=token)=(lane>>4)*4+reg.

#define H_DIM 2048
#define N_EXP 64
#define TOPK 8

typedef __attribute__((ext_vector_type(8))) short bf16x8;
typedef __attribute__((ext_vector_type(4))) float f32x4;

union FragU { uint4 q; unsigned u[4]; bf16x8 s; };

__device__ inline unsigned cvt_pk_bf16(float lo, float hi) {
  unsigned d;
  asm("v_cvt_pk_bf16_f32 %0, %1, %2" : "=v"(d) : "v"(lo), "v"(hi));
  return d;
}

// split 8 f32 (one A/B fragment worth) into 3 packed-bf16 fragments
__device__ inline void split3(const float* e, unsigned* dh, unsigned* dm,
                              unsigned* dl) {
#pragma unroll
  for (int p = 0; p < 4; ++p) {
    const float f0 = e[2 * p], f1 = e[2 * p + 1];
    const unsigned h = cvt_pk_bf16(f0, f1);
    const float r0 = f0 - __uint_as_float(h << 16);
    const float r1 = f1 - __uint_as_float(h & 0xffff0000u);
    const unsigned m = cvt_pk_bf16(r0, r1);
    const float s0 = r0 - __uint_as_float(m << 16);
    const float s1 = r1 - __uint_as_float(m & 0xffff0000u);
    dl[p] = cvt_pk_bf16(s0, s1);
    dh[p] = h;
    dm[p] = m;
  }
}

// ---- prologue: W[64][2048] f32 -> ws bf16x3 in B-fragment order ----
__global__ __launch_bounds__(256) void w_split_kernel(
    const float* __restrict__ w, uint4* __restrict__ ws) {
  const int id = blockIdx.x * 256 + threadIdx.x;  // 16384 threads
  const int l = id & 63;
  const int nt = (id >> 6) & 3;
  const int ksg = id >> 8;  // 0..63
  const int n = nt * 16 + (l & 15);
  const int kb = ksg * 32 + ((l >> 4) << 3);
  const float* wr = w + (size_t)n * H_DIM + kb;
  const float4 a = *(const float4*)(wr);
  const float4 b = *(const float4*)(wr + 4);
  const float e[8] = {a.x, a.y, a.z, a.w, b.x, b.y, b.z, b.w};
  unsigned dh[4], dm[4], dl[4];
  split3(e, dh, dm, dl);
  const int base = (ksg * 12 + nt * 3) * 64 + l;  // frag i=nt*3+sp stride 64
  ws[base] = make_uint4(dh[0], dh[1], dh[2], dh[3]);
  ws[base + 64] = make_uint4(dm[0], dm[1], dm[2], dm[3]);
  ws[base + 128] = make_uint4(dl[0], dl[1], dl[2], dl[3]);
}

// ---- main kernel ----
__global__ __launch_bounds__(512, 2) void moe_gate_kernel(
    const float* __restrict__ x, const uint4* __restrict__ wf_g,
    float* __restrict__ out, int n_tokens) {
  __shared__ float part[8 * 2048];      // 64 KB: per-wave C fragments
  __shared__ float logits[N_EXP * 64];  // 16 KB

  const int tid = threadIdx.x;
  const int l = tid & 63;
  const int w = tid >> 6;
  const int tp = w & 1;   // token half (32 tokens)
  const int kq = w >> 1;  // k quarter (512 k)
  const int t0 = blockIdx.x * 64;

  // x A-frag addresses: tile t in {0,1}: row = t0+tp*32+t*16+(l&15),
  // col = kq*512 + s*32 + (l>>4)*8 + h*4
  const float* xp0 =
      x + (size_t)(t0 + tp * 32 + (l & 15)) * H_DIM + kq * 512 + ((l >> 4) << 3);
  const float* xp1 = xp0 + (size_t)16 * H_DIM;

  f32x4 acc[2][4];
#pragma unroll
  for (int t = 0; t < 2; ++t)
#pragma unroll
    for (int nt = 0; nt < 4; ++nt) acc[t][nt] = (f32x4){0.f, 0.f, 0.f, 0.f};

  // depth-2 x prefetch registers
  float4 xa[2][2], xb[2][2], xc[2][2];
  xa[0][0] = *(const float4*)(xp0);
  xa[0][1] = *(const float4*)(xp0 + 4);
  xa[1][0] = *(const float4*)(xp1);
  xa[1][1] = *(const float4*)(xp1 + 4);
  xb[0][0] = *(const float4*)(xp0 + 32);
  xb[0][1] = *(const float4*)(xp0 + 36);
  xb[1][0] = *(const float4*)(xp1 + 32);
  xb[1][1] = *(const float4*)(xp1 + 36);

  const uint4* wbase = wf_g + (size_t)(kq * 16) * 768 + l;

#pragma unroll 1
  for (int s = 0; s < 16; ++s) {
    // B-frags for this step: 12 coalesced dwordx4 (L2-resident ws)
    uint4 wf[12];
    const uint4* wb = wbase + (size_t)s * 768;
#pragma unroll
    for (int i = 0; i < 12; ++i) wf[i] = wb[i * 64];

    // x prefetch s+2
    if (s + 2 < 16) {
      const float* p0 = xp0 + (s + 2) * 32;
      const float* p1 = xp1 + (s + 2) * 32;
      xc[0][0] = *(const float4*)(p0);
      xc[0][1] = *(const float4*)(p0 + 4);
      xc[1][0] = *(const float4*)(p1);
      xc[1][1] = *(const float4*)(p1 + 4);
    }

    // convert current x -> A-frags (hides W L2 latency under VALU)
    bf16x8 ah[2], am[2], al[2];
#pragma unroll
    for (int t = 0; t < 2; ++t) {
      const float4 v0 = xa[t][0], v1 = xa[t][1];
      const float e[8] = {v0.x, v0.y, v0.z, v0.w, v1.x, v1.y, v1.z, v1.w};
      FragU uh, um, ul;
      split3(e, uh.u, um.u, ul.u);
      ah[t] = uh.s;
      am[t] = um.s;
      al[t] = ul.s;
    }

    // 48 MFMAs: 4 n-tiles x 2 m-tiles x 6 products
#pragma unroll
    for (int nt = 0; nt < 4; ++nt) {
      FragU bh, bm, bl;
      bh.q = wf[nt * 3 + 0];
      bm.q = wf[nt * 3 + 1];
      bl.q = wf[nt * 3 + 2];
#pragma unroll
      for (int t = 0; t < 2; ++t) {
        f32x4 c = acc[t][nt];
        c = __builtin_amdgcn_mfma_f32_16x16x32_bf16(ah[t], bh.s, c, 0, 0, 0);
        c = __builtin_amdgcn_mfma_f32_16x16x32_bf16(am[t], bh.s, c, 0, 0, 0);
        c = __builtin_amdgcn_mfma_f32_16x16x32_bf16(ah[t], bm.s, c, 0, 0, 0);
        c = __builtin_amdgcn_mfma_f32_16x16x32_bf16(al[t], bh.s, c, 0, 0, 0);
        c = __builtin_amdgcn_mfma_f32_16x16x32_bf16(ah[t], bl.s, c, 0, 0, 0);
        c = __builtin_amdgcn_mfma_f32_16x16x32_bf16(am[t], bm.s, c, 0, 0, 0);
        acc[t][nt] = c;
      }
    }

    // rotate prefetch buffers (static indices)
#pragma unroll
    for (int t = 0; t < 2; ++t)
#pragma unroll
      for (int h = 0; h < 2; ++h) {
        xa[t][h] = xb[t][h];
        xb[t][h] = xc[t][h];
      }
  }

  // ---- store per-wave C fragments (2048 floats/wave); reduce; top-8 ----
#pragma unroll
  for (int t = 0; t < 2; ++t)
#pragma unroll
    for (int nt = 0; nt < 4; ++nt)
      *(float4*)&part[w * 2048 + (t * 4 + nt) * 256 + l * 4] =
          make_float4(acc[t][nt][0], acc[t][nt][1], acc[t][nt][2],
                      acc[t][nt][3]);
  __syncthreads();

  for (int z = tid; z < N_EXP * 64; z += 512) {
    const int e = z >> 6, t64 = z & 63;
    const int tpz = t64 >> 5, tz = (t64 >> 4) & 1;
    const int qz = (t64 >> 2) & 3, rz = t64 & 3;
    const int lz = qz * 16 + (e & 15);
    const int ntz = e >> 4;
    const int idx = (tz * 4 + ntz) * 256 + lz * 4 + rz;
    float v = ((part[(0 * 2 + tpz) * 2048 + idx] +
                part[(1 * 2 + tpz) * 2048 + idx]) +
               (part[(2 * 2 + tpz) * 2048 + idx] +
                part[(3 * 2 + tpz) * 2048 + idx]));
    logits[z] = v;  // z = e*64 + t64
  }
  __syncthreads();

  if (w != 0) return;

  // ---- wave 0: per-lane top-8 over 64 logits (lane = token) ----
  float lg[N_EXP];
#pragma unroll
  for (int e = 0; e < N_EXP; ++e) lg[e] = logits[e * 64 + l];

  float bw[TOPK];
  int bi[TOPK];
#pragma unroll
  for (int k = 0; k < TOPK; ++k) {
    float m = lg[0];
    int mi = 0;
#pragma unroll
    for (int e = 1; e < N_EXP; ++e) {
      if (lg[e] > m) {  // strict > keeps lowest index on tie (lax.top_k)
        m = lg[e];
        mi = e;
      }
    }
    bw[k] = m;
    bi[k] = mi;
#pragma unroll
    for (int e = 0; e < N_EXP; ++e)
      if (e == mi) lg[e] = -INFINITY;
  }

  // softmax over top-8 == full softmax renormalized to top-8 (exact)
  const float mx = bw[0];
  float ew[TOPK];
  float s = 0.f;
#pragma unroll
  for (int k = 0; k < TOPK; ++k) {
    ew[k] = expf(bw[k] - mx);
    s += ew[k];
  }
  const float inv = 1.f / s;

  float4 w0, w1, i0, i1;
  w0.x = ew[0] * inv; w0.y = ew[1] * inv; w0.z = ew[2] * inv; w0.w = ew[3] * inv;
  w1.x = ew[4] * inv; w1.y = ew[5] * inv; w1.z = ew[6] * inv; w1.w = ew[7] * inv;
  i0.x = (float)bi[0]; i0.y = (float)bi[1]; i0.z = (float)bi[2]; i0.w = (float)bi[3];
  i1.x = (float)bi[4]; i1.y = (float)bi[5]; i1.z = (float)bi[6]; i1.w = (float)bi[7];

  const int t = t0 + l;
  float4* ow = reinterpret_cast<float4*>(out + (size_t)t * TOPK);
  ow[0] = w0;
  ow[1] = w1;
  float4* oi =
      reinterpret_cast<float4*>(out + (size_t)n_tokens * TOPK + (size_t)t * TOPK);
  oi[0] = i0;
  oi[1] = i1;
}

extern "C" void kernel_launch(void* const* d_in, const int* in_sizes, int n_in,
                              void* d_out, int out_size, void* d_ws,
                              size_t ws_size, hipStream_t stream) {
  const float* x = (const float*)d_in[0];
  const float* w = (const float*)d_in[1];
  float* out = (float*)d_out;
  const int n_tokens = in_sizes[0] / H_DIM;  // 16384
  // prologue: split W into B-fragment-ordered bf16x3 (768 KB in d_ws)
  w_split_kernel<<<64, 256, 0, stream>>>(w, (uint4*)d_ws);
  const int n_blocks = n_tokens / 64;  // 256
  moe_gate_kernel<<<n_blocks, 512, 0, stream>>>(x, (const uint4*)d_ws, out,
                                                n_tokens);
}